// Round 8
// baseline (204.055 us; speedup 1.0000x reference)
//
#include <hip/hip_runtime.h>
#include <hip/hip_bf16.h>

// AttentionBlock: GroupNorm(8) -> QKV 1x1 -> softmax attention (hw=1024, c=256) -> proj + residual
// B=32, C=256, H=W=32. Inputs fp32, OUTPUT fp32. Internals bf16 MFMA, fp32 accum.
// R17:
//  - gn_apply DELETED. GroupNorm application fused into qkv_gemm's B-staging: block preamble
//    reduces gstats partials (128 loads + shfl_xor) into sM/sI[8]; B-panel is read as raw fp32 x
//    (channel-major), normalized in-register, transposed into Bs[128][72] (2-way-free writes,
//    R12-proven read pattern). B-prefetch for step k+1 issued before compute(k) (T14).
//    Saves: 1 launch + ~50MB traffic (xnT write+read, x re-read).
//  - attn / gn_stats / proj: unchanged from R16 (attn 55-58us = noise band, counters identical).
// ws: xnT (unused) | qtr 16MB | ktr 16MB | v 16MB | aoT 16MB | wbf 512KB | gstats 16KB.

typedef __bf16 bf16x8 __attribute__((ext_vector_type(8)));
typedef __bf16 bf16x4 __attribute__((ext_vector_type(4)));
typedef __bf16 bf16x2 __attribute__((ext_vector_type(2)));
typedef float f32x4 __attribute__((ext_vector_type(4)));
typedef float f32x16 __attribute__((ext_vector_type(16)));

#define MFMA16(a, b, c) __builtin_amdgcn_mfma_f32_16x16x32_bf16(a, b, c, 0, 0, 0)
#define MFMA32(a, b, c) __builtin_amdgcn_mfma_f32_32x32x16_bf16(a, b, c, 0, 0, 0)

#define GLD16(gsrc_, ldst_)                                                                  \
    __builtin_amdgcn_global_load_lds((const __attribute__((address_space(1))) void*)(gsrc_), \
                                     (__attribute__((address_space(3))) void*)(ldst_), 16, 0, 0)

// ---------------- K0: GN partial stats (2048 blocks) + fused weight convert ----------------
__global__ __launch_bounds__(256) void gn_stats(const float* __restrict__ x,
                                                float* __restrict__ stats,
                                                const float* __restrict__ wqkv,
                                                const float* __restrict__ wout,
                                                __bf16* __restrict__ wbf) {
    const int bid = blockIdx.x, t = threadIdx.x;
    // fused wconv on first 128 blocks: 128*256*8 = 262144 (wqkv 196608 | wout 65536)
    if (bid < 128) {
        int idx = (bid * 256 + t) * 8;
        const float* src = (idx < 196608) ? (wqkv + idx) : (wout + (idx - 196608));
        float4 v0 = *(const float4*)src;
        float4 v1 = *(const float4*)(src + 4);
        bf16x8 o;
        o[0] = (__bf16)v0.x; o[1] = (__bf16)v0.y; o[2] = (__bf16)v0.z; o[3] = (__bf16)v0.w;
        o[4] = (__bf16)v1.x; o[5] = (__bf16)v1.y; o[6] = (__bf16)v1.z; o[7] = (__bf16)v1.w;
        *(bf16x8*)&wbf[idx] = o;
    }
    // partial sums: group bg (0..255), part (0..7), 4096 floats per block
    const int bg = bid >> 3, part = bid & 7;
    const float* xp = x + (size_t)bg * 32768 + part * 4096;
    float s = 0.f, s2 = 0.f;
    #pragma unroll
    for (int i = 0; i < 4; i++) {
        float4 v = *(const float4*)(xp + (i * 256 + t) * 4);
        s  += v.x + v.y + v.z + v.w;
        s2 += v.x*v.x + v.y*v.y + v.z*v.z + v.w*v.w;
    }
    #pragma unroll
    for (int o = 32; o > 0; o >>= 1) { s += __shfl_down(s, o, 64); s2 += __shfl_down(s2, o, 64); }
    __shared__ float red[8];
    const int wv = t >> 6;
    if ((t & 63) == 0) { red[wv * 2] = s; red[wv * 2 + 1] = s2; }
    __syncthreads();
    if (t == 0) {
        float ts  = red[0] + red[2] + red[4] + red[6];
        float ts2 = red[1] + red[3] + red[5] + red[7];
        stats[bg * 16 + part * 2]     = ts;
        stats[bg * 16 + part * 2 + 1] = ts2;
    }
}

// ---------------- K2: QKV GEMM with fused GroupNorm on the B operand ----------------
// A (weights) staged via global_load_lds into XOR-swizzled As[128][64].
// B staged from raw x fp32: per k-step each thread loads 2 channels x 16 s (64B each),
// normalizes ((v-mean)*inv*ga+be), writes bf16x2 into Bs[s][c] (stride 72, 2-way-free).
__global__ __launch_bounds__(256) void qkv_gemm(const __bf16* __restrict__ wbf,
                                                const float* __restrict__ bias,
                                                const float* __restrict__ x,
                                                const float* __restrict__ gstats,
                                                const float* __restrict__ gw,
                                                const float* __restrict__ gb,
                                                __bf16* __restrict__ qtr,
                                                __bf16* __restrict__ ktr,
                                                __bf16* __restrict__ vbuf) {
    __shared__ union {
        struct { __bf16 A[128][64]; __bf16 B[128][72]; } g;   // 34816 B main loop
        __bf16 ct[128][136];                                  // 34816 B epilogue
    } sm;
    __shared__ float sM[8], sI[8];
    // T1 swizzle: 1536 wgs, 192/XCD; 6 m-blocks of one (b,n0) B-panel consecutive on one XCD
    const int lin = blockIdx.x + ((blockIdx.y + blockIdx.z * 6) << 3);
    const int xcd = lin & 7, idx = lin >> 3;
    const int gwk = xcd * 192 + idx;
    const int mt = gwk % 6, panel = gwk / 6;
    const int b = panel >> 3;
    const int n0 = (panel & 7) * 128, m0 = mt * 128;
    const int t = threadIdx.x;
    const int wave = t >> 6, lane = t & 63, quad = lane >> 4, l16 = lane & 15;
    const int wm = (wave & 1) * 64, wn = (wave >> 1) * 64;
    const __bf16* arow = wbf + (size_t)m0 * 256;
    auto As = sm.g.A;
    auto Bs = sm.g.B;

    // ---- preamble: reduce gstats partials for this b's 8 groups into sM/sI ----
    if (t < 128) {
        const int g = t >> 4, j = t & 15;
        float v = gstats[((size_t)b * 8 + g) * 16 + j];
        v += __shfl_xor(v, 2, 64);
        v += __shfl_xor(v, 4, 64);
        v += __shfl_xor(v, 8, 64);
        float w = __shfl_xor(v, 1, 64);       // at j==0: w = S2 total
        if (j == 0) {
            float mean = v / 32768.f;
            sM[g] = mean;
            sI[g] = rsqrtf(w / 32768.f - mean * mean + 1e-5f);
        }
    }
    __syncthreads();

    // ---- staging helpers ----
    const int cl = (t & 31) * 2;              // even c_local within 64-chunk
    const int sh = t >> 5;                    // 0..7 s-block
    float bpre[32];
    float nsc0, nof0, nsc1, nof1;

#define PREFETCH_B(KC_)                                                                 \
    {                                                                                   \
        const int ch = (KC_) + cl;                                                      \
        const int gg = ch >> 5;                                                         \
        const float* xb = x + (((size_t)b * 256 + ch) * 1024) + n0 + sh * 16;           \
        _Pragma("unroll")                                                               \
        for (int u = 0; u < 4; u++) *(float4*)&bpre[u * 4] = *(const float4*)(xb + u * 4); \
        _Pragma("unroll")                                                               \
        for (int u = 0; u < 4; u++) *(float4*)&bpre[16 + u * 4] = *(const float4*)(xb + 1024 + u * 4); \
        float m_ = sM[gg], iv_ = sI[gg];                                                \
        nsc0 = iv_ * gw[ch];     nof0 = gb[ch]     - m_ * nsc0;                         \
        nsc1 = iv_ * gw[ch + 1]; nof1 = gb[ch + 1] - m_ * nsc1;                         \
    }

#define WRITE_B()                                                                       \
    {                                                                                   \
        _Pragma("unroll")                                                               \
        for (int i = 0; i < 16; i++) {                                                  \
            bf16x2 e;                                                                   \
            e[0] = (__bf16)(bpre[i] * nsc0 + nof0);                                     \
            e[1] = (__bf16)(bpre[16 + i] * nsc1 + nof1);                                \
            *(bf16x2*)&Bs[sh * 16 + i][cl] = e;                                         \
        }                                                                               \
    }

#define GLD_A(KC_)                                                                      \
    {                                                                                   \
        _Pragma("unroll")                                                               \
        for (int i = 0; i < 4; i++) {                                                   \
            const int ch_ = wave * 4 + i;                                               \
            const int r_ = ch_ * 8 + (lane >> 3);                                       \
            const int sw_ = ((lane & 7) ^ (r_ & 7)) * 8;                                \
            GLD16(arow + (size_t)r_ * 256 + (KC_) + sw_, (char*)&As[0][0] + ch_ * 1024); \
        }                                                                               \
    }

    f32x4 acc[4][4] = {};

    // prologue: stage k-step 0
    PREFETCH_B(0)
    GLD_A(0)
    WRITE_B()
    __syncthreads();

    for (int kk = 0; kk < 4; kk++) {
        if (kk < 3) PREFETCH_B((kk + 1) * 64)      // loads fly under MFMA below
        #pragma unroll
        for (int kh = 0; kh < 2; kh++) {
            bf16x8 af[4], bfv[4];
            #pragma unroll
            for (int im = 0; im < 4; im++) {
                const int row = wm + im * 16 + l16;
                af[im] = *(const bf16x8*)&As[row][(((kh * 4 + quad) ^ (row & 7)) * 8)];
            }
            #pragma unroll
            for (int in = 0; in < 4; in++)
                bfv[in] = *(const bf16x8*)&Bs[wn + in * 16 + l16][kh * 32 + quad * 8];
            #pragma unroll
            for (int im = 0; im < 4; im++)
                #pragma unroll
                for (int in = 0; in < 4; in++)
                    acc[im][in] = MFMA16(af[im], bfv[in], acc[im][in]);
        }
        __syncthreads();
        if (kk < 3) {
            GLD_A((kk + 1) * 64)
            WRITE_B()
            __syncthreads();
        }
    }
#undef PREFETCH_B
#undef WRITE_B
#undef GLD_A

    if (m0 < 512) {
        // q/k path: transpose C-tile into LDS [s][c], then coalesced bf16x8 stores.
        #pragma unroll
        for (int im = 0; im < 4; im++) {
            #pragma unroll
            for (int in = 0; in < 4; in++) {
                int ob = m0 + wm + im * 16 + quad * 4;
                bf16x4 ov;
                #pragma unroll
                for (int r = 0; r < 4; r++) ov[r] = (__bf16)(acc[im][in][r] + bias[ob + r]);
                *(bf16x4*)&sm.ct[wn + in * 16 + l16][wm + im * 16 + quad * 4] = ov;
            }
        }
        __syncthreads();
        {
            const int rbase = t >> 2, cf = t & 3;
            #pragma unroll
            for (int rr = 0; rr < 2; rr++) {
                int row = rbase + rr * 64;
                int sg = n0 + row;
                __bf16* dst = (m0 < 256) ? &qtr[((size_t)b * 1024 + sg) * 256 + m0]
                                         : &ktr[((size_t)b * 1024 + sg) * 256 + (m0 - 256)];
                #pragma unroll
                for (int u = 0; u < 4; u++) {
                    int colb = cf * 8 + u * 32;
                    *(bf16x8*)&dst[colb] = *(const bf16x8*)&sm.ct[row][colb];
                }
            }
        }
    } else {
        // v path: stage C-tile into LDS as [c][t], then fully-coalesced b128 stores to vbuf [b][c][t].
        #pragma unroll
        for (int im = 0; im < 4; im++) {
            #pragma unroll
            for (int in = 0; in < 4; in++) {
                int cc = wm + im * 16 + quad * 4;
                int tl = wn + in * 16 + l16;
                #pragma unroll
                for (int r = 0; r < 4; r++)
                    sm.ct[cc + r][tl] = (__bf16)(acc[im][in][r] + bias[m0 + cc + r]);
            }
        }
        __syncthreads();
        {
            const int row = t >> 1, tc = (t & 1) * 64;   // c_local row, t-chunk base
            const int cglob = m0 - 512 + row;
            __bf16* dst = &vbuf[((size_t)b * 256 + cglob) * 1024 + n0 + tc];
            #pragma unroll
            for (int u = 0; u < 8; u++)
                *(bf16x8*)&dst[u * 8] = *(const bf16x8*)&sm.ct[row][tc + u * 8];
        }
    }
}

// ---------------- K3: fused flash attention (R12 structure: swapped QK^T, permuted-V, T14 prefetch) ----------------
__global__ __launch_bounds__(512, 2) void attn_kernel(const __bf16* __restrict__ qtr,
                                                      const __bf16* __restrict__ ktr,
                                                      const __bf16* __restrict__ vbuf,
                                                      __bf16* __restrict__ aoT) {
    __shared__ __bf16 Kt[2][32][260];     // [t-half][t_local][c]
    __shared__ __bf16 Vs[2][256][36];     // [t-half][c][slot]  (slot = permuted t within 16-chunks)
    __shared__ bf16x8 Pl[4][2][2][64];    // [pair][th][chunk][lane] P-fragments for partner wave
    __shared__ float Lred[4][2][32];      // [pair][th][s_local]
    const int b = blockIdx.x;
    const int tid = threadIdx.x;
    const int wave = tid >> 6, lane = tid & 63, half = lane >> 5, l31 = lane & 31;
    const int pair = wave & 3, th = wave >> 2;
    const int s0 = blockIdx.y * 128 + pair * 32;
    const float kscale = 0.09016844f;   // (1/16) * log2(e); p = exp2(s * kscale)

    // Q fragments (B-operand of swapped QK: lane = s-col, elems = c)
    bf16x8 aq[16];
    #pragma unroll
    for (int ks = 0; ks < 16; ks++)
        aq[ks] = *(const bf16x8*)&qtr[((size_t)b * 1024 + s0 + l31) * 256 + ks * 16 + half * 8];

    const int k_row = tid >> 3;
    const int k_cb  = (tid & 7) * 8;
    const int v_c   = tid >> 1;
    const int v_th  = tid & 1;
    const size_t kbase = (size_t)b * 1024 * 256;
    const size_t vbase = (size_t)b * 256 * 1024;

    float l_acc = 0.f;
    f32x16 o_acc[4] = {};

    // prologue: prefetch tile 0 into registers
    bf16x8 kpre[4], vpre[4];
    #pragma unroll
    for (int u = 0; u < 4; u++) {
        kpre[u] = *(const bf16x8*)&ktr[kbase + (size_t)k_row * 256 + k_cb + u * 64];
        vpre[u] = *(const bf16x8*)&vbuf[vbase + (size_t)v_c * 1024 + v_th * 32 + u * 8];
    }

    for (int it = 0; it < 16; it++) {
        // stage K (linear) and V (slot-permuted: within each 16-t chunk, t-groups [0-3,4-7,8-11,12-15]
        // land at slots [0-3,8-11,4-7,12-15] so p-register order matches MFMA k-slots)
        #pragma unroll
        for (int u = 0; u < 4; u++)
            *(bf16x8*)&Kt[k_row >> 5][k_row & 31][k_cb + u * 64] = kpre[u];
        #pragma unroll
        for (int u = 0; u < 4; u++) {
            const bf16x4* hv = (const bf16x4*)&vpre[u];
            const int sbase = (u >> 1) * 16 + (u & 1) * 4;   // 0,4,16,20
            *(bf16x4*)&Vs[v_th][v_c][sbase]     = hv[0];
            *(bf16x4*)&Vs[v_th][v_c][sbase + 8] = hv[1];
        }
        __syncthreads();
        // T14: issue next tile's global loads NOW — they fly under QK + softmax
        if (it < 15) {
            const int t1 = (it + 1) * 64;
            #pragma unroll
            for (int u = 0; u < 4; u++) {
                kpre[u] = *(const bf16x8*)&ktr[kbase + (size_t)(t1 + k_row) * 256 + k_cb + u * 64];
                vpre[u] = *(const bf16x8*)&vbuf[vbase + (size_t)v_c * 1024 + t1 + v_th * 32 + u * 8];
            }
        }

        // swapped QK^T: A = K (lane = t-row), B = Q (lane = s-col) -> C: regs = t, lane = s
        f32x16 sc_a = {}, sc_b = {};
        __builtin_amdgcn_s_setprio(1);
        #pragma unroll
        for (int ks = 0; ks < 8; ks++) {
            bf16x8 bk0 = *(const bf16x8*)&Kt[th][l31][ks * 16 + half * 8];
            bf16x8 bk1 = *(const bf16x8*)&Kt[th][l31][(ks + 8) * 16 + half * 8];
            sc_a = MFMA32(bk0, aq[ks], sc_a);
            sc_b = MFMA32(bk1, aq[ks + 8], sc_b);
        }
        __builtin_amdgcn_s_setprio(0);

        // softmax partial + P fragments (lane = s, regs = t -> direct PV A-operand)
        bf16x8 pf0, pf1;
        #pragma unroll
        for (int r = 0; r < 8; r++) {
            float p = exp2f((sc_a[r] + sc_b[r]) * kscale);
            l_acc += p;
            pf0[r] = (__bf16)p;
        }
        #pragma unroll
        for (int r = 8; r < 16; r++) {
            float p = exp2f((sc_a[r] + sc_b[r]) * kscale);
            l_acc += p;
            pf1[r - 8] = (__bf16)p;
        }
        Pl[pair][th][0][lane] = pf0;
        Pl[pair][th][1][lane] = pf1;
        __syncthreads();
        bf16x8 pp0 = Pl[pair][1 - th][0][lane];
        bf16x8 pp1 = Pl[pair][1 - th][1][lane];

        bf16x8 ap[4];
        if (th == 0) { ap[0] = pf0; ap[1] = pf1; ap[2] = pp0; ap[3] = pp1; }
        else         { ap[0] = pp0; ap[1] = pp1; ap[2] = pf0; ap[3] = pf1; }

        __builtin_amdgcn_s_setprio(1);
        #pragma unroll
        for (int n = 0; n < 4; n++) {
            int c = th * 128 + n * 32 + l31;
            #pragma unroll
            for (int kc = 0; kc < 4; kc++) {
                bf16x8 bv = *(const bf16x8*)&Vs[kc >> 1][c][(kc & 1) * 16 + half * 8];
                o_acc[n] = MFMA32(ap[kc], bv, o_acc[n]);
            }
        }
        __builtin_amdgcn_s_setprio(0);
        __syncthreads();
    }

    // l reduction: combine lane-halves (same s), then th-pairs via LDS
    l_acc += __shfl_xor(l_acc, 32, 64);
    if (lane < 32) Lred[pair][th][l31] = l_acc;
    __syncthreads();
    #pragma unroll
    for (int r = 0; r < 16; r++) {
        int row = (r & 3) + 8 * (r >> 2) + 4 * half;
        float rinv = 1.0f / (Lred[pair][0][row] + Lred[pair][1][row]);
        #pragma unroll
        for (int n = 0; n < 4; n++) {
            int c = th * 128 + n * 32 + l31;
            aoT[((size_t)b * 1024 + s0 + row) * 256 + c] = (__bf16)(o_acc[n][r] * rinv);
        }
    }
}

// ---------------- 128x128 GEMM body (proj): 2-phase counted-vmcnt pipeline ----------------
#define GEMM64P_BODY(ArowBase_, BrowBase_)                                              \
    f32x4 acc[4][4] = {};                                                               \
    {                                                                                   \
        _Pragma("unroll")                                                               \
        for (int i = 0; i < 4; i++) {                                                   \
            const int ch = wave * 4 + i;                                                \
            const int r = ch * 8 + (lane >> 3);                                         \
            const int sw = ((lane & 7) ^ (r & 7)) * 8;                                  \
            GLD16((ArowBase_) + (size_t)r * 256 + sw, (char*)&As[0][0][0] + ch * 1024); \
            GLD16((BrowBase_) + (size_t)r * 256 + sw, (char*)&Bs[0][0][0] + ch * 1024); \
        }                                                                               \
    }                                                                                   \
    _Pragma("unroll")                                                                   \
    for (int kk = 0; kk < 4; kk++) {                                                    \
        if (kk < 3) {                                                                   \
            _Pragma("unroll")                                                           \
            for (int i = 0; i < 4; i++) {                                               \
                const int ch = wave * 4 + i;                                            \
                const int r = ch * 8 + (lane >> 3);                                     \
                const int sw = ((lane & 7) ^ (r & 7)) * 8;                              \
                GLD16((ArowBase_) + (size_t)r * 256 + (kk + 1) * 64 + sw,               \
                      (char*)&As[(kk + 1) & 1][0][0] + ch * 1024);                      \
                GLD16((BrowBase_) + (size_t)r * 256 + (kk + 1) * 64 + sw,               \
                      (char*)&Bs[(kk + 1) & 1][0][0] + ch * 1024);                      \
            }                                                                           \
            asm volatile("s_waitcnt vmcnt(8)" ::: "memory");                            \
        } else {                                                                        \
            asm volatile("s_waitcnt vmcnt(0)" ::: "memory");                            \
        }                                                                               \
        asm volatile("s_barrier" ::: "memory");                                         \
        _Pragma("unroll")                                                               \
        for (int kh = 0; kh < 2; kh++) {                                                \
            bf16x8 af[4], bfv[4];                                                       \
            _Pragma("unroll")                                                           \
            for (int im = 0; im < 4; im++) {                                            \
                const int row = wm + im * 16 + l16;                                     \
                af[im] = *(const bf16x8*)&As[kk & 1][row][(((kh * 4 + quad) ^ (row & 7)) * 8)]; \
            }                                                                           \
            _Pragma("unroll")                                                           \
            for (int in = 0; in < 4; in++) {                                            \
                const int row = wn + in * 16 + l16;                                     \
                bfv[in] = *(const bf16x8*)&Bs[kk & 1][row][(((kh * 4 + quad) ^ (row & 7)) * 8)]; \
            }                                                                           \
            _Pragma("unroll")                                                           \
            for (int im = 0; im < 4; im++)                                              \
                _Pragma("unroll")                                                       \
                for (int in = 0; in < 4; in++)                                          \
                    acc[im][in] = MFMA16(af[im], bfv[in], acc[im][in]);                 \
        }                                                                               \
        asm volatile("s_waitcnt lgkmcnt(0)" ::: "memory");                              \
        asm volatile("s_barrier" ::: "memory");                                        \
    }

// ---------------- K4: proj GEMM, 128x128 tiles, XCD-chunked swizzle ----------------
__global__ __launch_bounds__(256) void proj_gemm(const __bf16* __restrict__ wbf_out,
                                                 const float* __restrict__ bias,
                                                 const __bf16* __restrict__ aoT,
                                                 const float* __restrict__ resid,
                                                 float* __restrict__ Out) {
    __shared__ union {
        struct { __bf16 A[2][128][64]; __bf16 B[2][128][64]; } g;  // 65536 B dbuf main loop
        float cf[64][132];                                         // 33792 B epilogue (m-half)
    } sm;
    // T1 swizzle: 512 wgs, 64/XCD; 2 m-blocks of one (b,n0) B-panel consecutive on one XCD
    const int lin = blockIdx.x + ((blockIdx.y + blockIdx.z * 2) << 3);
    const int xcd = lin & 7, idx = lin >> 3;
    const int gwk = xcd * 64 + idx;
    const int mt = gwk & 1, panel = gwk >> 1;
    const int b = panel >> 3;
    const int n0 = (panel & 7) * 128, m0 = mt * 128;
    const int t = threadIdx.x;
    const int wave = t >> 6, lane = t & 63, quad = lane >> 4, l16 = lane & 15;
    const int wm = (wave & 1) * 64, wn = (wave >> 1) * 64;
    const __bf16* arow = wbf_out + (size_t)m0 * 256;
    const __bf16* brow = aoT + ((size_t)b * 1024 + n0) * 256;
    auto As = sm.g.A;
    auto Bs = sm.g.B;

    GEMM64P_BODY(arow, brow)

    for (int h = 0; h < 2; h++) {
        if ((wave & 1) == h) {
            #pragma unroll
            for (int im = 0; im < 4; im++)
                #pragma unroll
                for (int in = 0; in < 4; in++)
                    #pragma unroll
                    for (int r = 0; r < 4; r++)
                        sm.cf[im * 16 + quad * 4 + r][wn + in * 16 + l16] = acc[im][in][r];
        }
        __syncthreads();
        {
            const int rloc = t >> 2, cq = (t & 3) * 4;
            const int o = m0 + h * 64 + rloc;
            const float bo = bias[o];
            const float* rrow = &resid[((size_t)b * 256 + o) * 1024 + n0];
            float* orow = &Out[((size_t)b * 256 + o) * 1024 + n0];
            #pragma unroll
            for (int u = 0; u < 8; u++) {
                int col = cq + u * 16;
                f32x4 cv = *(const f32x4*)&sm.cf[rloc][col];
                float4 rv = *(const float4*)&rrow[col];
                float4 ov;
                ov.x = cv[0] + bo + rv.x;
                ov.y = cv[1] + bo + rv.y;
                ov.z = cv[2] + bo + rv.z;
                ov.w = cv[3] + bo + rv.w;
                *(float4*)&orow[col] = ov;
            }
        }
        __syncthreads();
    }
}

extern "C" void kernel_launch(void* const* d_in, const int* in_sizes, int n_in,
                              void* d_out, int out_size, void* d_ws, size_t ws_size,
                              hipStream_t stream) {
    const float* x    = (const float*)d_in[0];
    const float* gw   = (const float*)d_in[1];
    const float* gb   = (const float*)d_in[2];
    const float* wqkv = (const float*)d_in[3];
    const float* bqkv = (const float*)d_in[4];
    const float* wout = (const float*)d_in[5];
    const float* bout = (const float*)d_in[6];
    float* out = (float*)d_out;

    const size_t T16 = (size_t)32 * 1024 * 256;
    __bf16* xnT  = (__bf16*)d_ws;        // (unused this round)
    __bf16* qtr  = xnT + T16;            // [b][s][c]
    __bf16* ktr  = qtr + T16;            // [b][t][c]
    __bf16* vbuf = ktr + T16;            // [b][c][t]
    __bf16* aoT  = vbuf + T16;           // [b][s][c]
    __bf16* wbf  = aoT + T16;            // wqkv_bf16 (196608) | wout_bf16 (65536)
    float* gstats = (float*)(wbf + 262144);  // [256 groups][8 parts][2]

    gn_stats<<<dim3(2048), 256, 0, stream>>>(x, gstats, wqkv, wout, wbf);
    qkv_gemm<<<dim3(8, 6, 32), 256, 0, stream>>>(wbf, bqkv, x, gstats, gw, gb, qtr, ktr, vbuf);
    attn_kernel<<<dim3(32, 8), 512, 0, stream>>>(qtr, ktr, vbuf, aoT);
    proj_gemm<<<dim3(8, 2, 32), 256, 0, stream>>>(wbf + 196608, bout, aoT, x, out);
}